// Round 11
// baseline (207.547 us; speedup 1.0000x reference)
//
#include <hip/hip_runtime.h>
#include <hip/hip_bf16.h>
#include <cmath>

typedef __bf16 bf16_t;
typedef __bf16 bf16x8 __attribute__((ext_vector_type(8)));
typedef float  f32x4  __attribute__((ext_vector_type(4)));

#define AS1(p) ((__attribute__((address_space(1))) void*)(p))
#define AS3(p) ((__attribute__((address_space(3))) void*)(p))

// N=8192, H=512, TAU=0.5, EPS=1e-8
// exp(x) = exp2(x * log2e / TAU); (1/0.5)*log2e = 2.885390...
#define C_EXP2 2.8853900817779268f
#define NROWS  8192
#define HDIM   512

// ---------------------------------------------------------------- f32->bf16
__global__ __launch_bounds__(256) void cvt_f32_bf16(const float* __restrict__ src,
                                                    bf16_t* __restrict__ dst, int n8) {
    int i = blockIdx.x * 256 + threadIdx.x;
    if (i >= n8) return;
    const f32x4* s4 = (const f32x4*)src;
    f32x4 a = s4[2 * (size_t)i];
    f32x4 b = s4[2 * (size_t)i + 1];
    bf16x8 o;
#pragma unroll
    for (int j = 0; j < 4; ++j) { o[j] = (bf16_t)a[j]; o[4 + j] = (bf16_t)b[j]; }
    *(bf16x8*)(dst + 8 * (size_t)i) = o;
}

// ---------------------------------------------------------------- MLP GEMM (NT)
// 128x128 tile, BK=64, NT=8, 2-deep dbuf, vmcnt(0)/step (proven R8 structure).
// EPI=1: bias+ELU -> bf16   EPI=2: bias -> f32 (d_out) + bf16 copy
template <int EPI>
__global__ __launch_bounds__(256, 2)
void gemm_bt(const bf16_t* __restrict__ A, const bf16_t* __restrict__ B,
             const float* __restrict__ bias,
             bf16_t* __restrict__ outb, float* __restrict__ outf) {
    constexpr int K  = 512;
    constexpr int NT = 8;
    __shared__ __align__(16) char smem[65536];

    const int tid  = threadIdx.x;
    const int lane = tid & 63;
    const int wv   = tid >> 6;
    const int wm   = wv >> 1;
    const int wn   = wv & 1;

    const long ibase = (long)blockIdx.x * 128;
    const long jbase = (long)blockIdx.y * 128;

    const int r8  = lane >> 3;
    const int c16 = lane & 7;
    const long aSrc0 = (ibase + wv * 32 + r8) * (long)K + ((c16 ^ r8) << 3);
    const long bSrc0 = (jbase + wv * 32 + r8) * (long)K + ((c16 ^ r8) << 3);

    f32x4 acc[4][4] = {};
    const int fr = lane & 15;
    const int fj = lane >> 4;
    const int crow = fj << 2;
    const int ccol = fr;

#pragma unroll
    for (int s = 0; s < 4; ++s) {
        const int ro = (wv * 32 + s * 8) * 128;
        __builtin_amdgcn_global_load_lds(AS1(A + aSrc0 + s * 8 * K), AS3(smem + ro), 16, 0, 0);
        __builtin_amdgcn_global_load_lds(AS1(B + bSrc0 + s * 8 * K), AS3(smem + 32768 + ro), 16, 0, 0);
    }
    asm volatile("s_waitcnt vmcnt(0)" ::: "memory");
    __builtin_amdgcn_s_barrier();
    asm volatile("" ::: "memory");

#pragma unroll
    for (int t = 0; t < NT; ++t) {
        if (t + 1 < NT) {
            const int nb = (t + 1) & 1;
#pragma unroll
            for (int s = 0; s < 4; ++s) {
                const int ro = (wv * 32 + s * 8) * 128;
                __builtin_amdgcn_global_load_lds(AS1(A + aSrc0 + s * 8 * K + (t + 1) * 64),
                                                 AS3(smem + nb * 16384 + ro), 16, 0, 0);
                __builtin_amdgcn_global_load_lds(AS1(B + bSrc0 + s * 8 * K + (t + 1) * 64),
                                                 AS3(smem + 32768 + nb * 16384 + ro), 16, 0, 0);
            }
        }
        asm volatile("" ::: "memory");
#pragma unroll
        for (int kk = 0; kk < 2; ++kk) {
            bf16x8 af[4], bfr[4];
#pragma unroll
            for (int m = 0; m < 4; ++m) {
                const int row = wm * 64 + m * 16 + fr;
                af[m] = *(const bf16x8*)(smem + (t & 1) * 16384 + row * 128 +
                                         (((kk * 4 + fj) ^ (fr & 7)) << 4));
            }
#pragma unroll
            for (int n = 0; n < 4; ++n) {
                const int row = wn * 64 + n * 16 + fr;
                bfr[n] = *(const bf16x8*)(smem + 32768 + (t & 1) * 16384 + row * 128 +
                                          (((kk * 4 + fj) ^ (fr & 7)) << 4));
            }
            __builtin_amdgcn_s_setprio(1);
#pragma unroll
            for (int m = 0; m < 4; ++m)
#pragma unroll
                for (int n = 0; n < 4; ++n)
                    acc[m][n] = __builtin_amdgcn_mfma_f32_16x16x32_bf16(af[m], bfr[n],
                                                                        acc[m][n], 0, 0, 0);
            __builtin_amdgcn_s_setprio(0);
        }
        asm volatile("" ::: "memory");
        if (t + 1 < NT) asm volatile("s_waitcnt vmcnt(0)" ::: "memory");
        __builtin_amdgcn_s_barrier();
        asm volatile("" ::: "memory");
    }

#pragma unroll
    for (int m = 0; m < 4; ++m) {
        const long rowb = ibase + wm * 64 + m * 16 + crow;
#pragma unroll
        for (int n = 0; n < 4; ++n) {
            const int col = (int)jbase + wn * 64 + n * 16 + ccol;
            const float bv = bias[col];
#pragma unroll
            for (int r = 0; r < 4; ++r) {
                float v = acc[m][n][r] + bv;
                const long idx = (rowb + r) * HDIM + col;
                if constexpr (EPI == 1) {
                    v = v > 0.f ? v : expm1f(v);  // ELU(alpha=1)
                    outb[idx] = (bf16_t)v;
                } else {
                    outf[idx] = v;
                    outb[idx] = (bf16_t)v;
                }
            }
        }
    }
}

// ---------------------------------------------------------------- GEMM3 + pos
// 128(i) x 128(j) tile, 512 threads = 8 waves: wi=wv>>2 (64-row slab),
// wj=wv&3 (32-col slab); wave-tile 64x32 -> acc[4][2] (32 regs).
// BK=64, NT=8, 2-deep dbuf = 64 KB LDS -> 2 blocks/CU = 4 waves/SIMD (the
// TLP that R9/R10's 1-block/CU config lacked; every latency was exposed).
// SWAPPED MFMA: acc[mi][nj] = mfma(bfr[nj], af[mi], .) => D col(lane&15)=i,
// D reg=j -> pos loads directly in fragment layout: pv[4][2] f32x4 (32 regs).
// Ledger/step: issue S(t+1)[4/thread] then pv(t)[1/thread]; end-of-step
// vmcnt(1) drains S(t+1)+pv(t-1), pv(t) floats across the barrier.
// Register budget at __launch_bounds__(512,4): cap 128 = acc 32 + pv 32 + ~50.
__global__ __launch_bounds__(512, 4)
void gemm_pos(const bf16_t* __restrict__ A, const bf16_t* __restrict__ B,
              const float* __restrict__ rn0, const float* __restrict__ rn1,
              const float* __restrict__ pos,
              float* __restrict__ pS, float* __restrict__ pP) {
    constexpr int K = 512;
    // As dbuf: [0,32K) (2 x 16 KB); Bs dbuf: [32K,64K) (2 x 16 KB)
    __shared__ __align__(16) char smem[65536];

    const int tid  = threadIdx.x;
    const int lane = tid & 63;
    const int wv   = tid >> 6;   // 0..7
    const int wi   = wv >> 2;    // 0..1: 64-row (i) slab
    const int wj   = wv & 3;     // 0..3: 32-col (j) slab

    // bijective XCD swizzle (4096 blocks % 8 == 0)
    const int flat = blockIdx.x;
    const int swz  = (flat & 7) * 512 + (flat >> 3);
    const long ibase = (long)(swz & 63) * 128;
    const int  jt    = swz >> 6;        // 0..63
    const long jbase = (long)jt * 128;

    const int r8  = lane >> 3;
    const int c16 = lane & 7;
    const long aSrc0 = (ibase + wv * 16 + r8) * (long)K + ((c16 ^ r8) << 3);
    const long bSrc0 = (jbase + wv * 16 + r8) * (long)K + ((c16 ^ r8) << 3);

    f32x4 acc[4][2] = {};
    const int fr = lane & 15;   // i within 16 (C col after swap)
    const int fj = lane >> 4;
    const int crow = fj << 2;   // j base within fragment
    const int ccol = fr;

    // scales (prologue loads, drained by vmcnt(0))
    float r0v[4], r1v[8];
#pragma unroll
    for (int mi = 0; mi < 4; ++mi)
        r0v[mi] = rn0[ibase + wi * 64 + mi * 16 + ccol] * C_EXP2;
#pragma unroll
    for (int nj = 0; nj < 2; ++nj)
#pragma unroll
        for (int r = 0; r < 4; ++r)
            r1v[nj * 4 + r] = rn1[jbase + wj * 32 + nj * 16 + crow + r];

    f32x4 pv[4][2];  // pos fragments: pv[mi][nj] = pos[i][j..j+3]
    const float* p00 = pos + (size_t)(ibase + wi * 64 + ccol) * NROWS + jbase + wj * 32 + crow;

    // staging: A,B each 128x64 bf16 = 16 KB/buf; 2 instr/thread each
    auto STAGE = [&](int buf, int t) {
#pragma unroll
        for (int s = 0; s < 2; ++s)
            __builtin_amdgcn_global_load_lds(AS1(A + aSrc0 + s * 8 * K + t * 64),
                                             AS3(smem + buf * 16384 + (wv * 16 + s * 8) * 128), 16, 0, 0);
#pragma unroll
        for (int s = 0; s < 2; ++s)
            __builtin_amdgcn_global_load_lds(AS1(B + bSrc0 + s * 8 * K + t * 64),
                                             AS3(smem + 32768 + buf * 16384 + (wv * 16 + s * 8) * 128), 16, 0, 0);
    };

    // ---------------- prologue: stage(0), full drain, barrier
    STAGE(0, 0);
    asm volatile("s_waitcnt vmcnt(0)" ::: "memory");
    __builtin_amdgcn_s_barrier();
    asm volatile("" ::: "memory");

    // ---------------- pipelined K-loop (fully unrolled)
#pragma unroll
    for (int t = 0; t < 8; ++t) {
        if (t + 1 < 8) STAGE((t + 1) & 1, t + 1);
        asm volatile("" ::: "memory");  // pin: pv(t) issues AFTER S(t+1)
        {
            const int mi = t >> 1, nj = t & 1;   // compile-time
            pv[mi][nj] = *(const f32x4*)(p00 + (size_t)(mi * 16) * NROWS + nj * 16);
        }
        // compute on buf t&1: 2 k-halves x (4 A-frag x 2 B-frag) MFMA
#pragma unroll
        for (int kk = 0; kk < 2; ++kk) {
            bf16x8 af[4], bfr[2];
#pragma unroll
            for (int mi = 0; mi < 4; ++mi) {
                const int row = wi * 64 + mi * 16 + fr;
                af[mi] = *(const bf16x8*)(smem + (t & 1) * 16384 + row * 128 +
                                          (((kk * 4 + fj) ^ (fr & 7)) << 4));
            }
#pragma unroll
            for (int nj = 0; nj < 2; ++nj) {
                const int row = wj * 32 + nj * 16 + fr;
                bfr[nj] = *(const bf16x8*)(smem + 32768 + (t & 1) * 16384 + row * 128 +
                                           (((kk * 4 + fj) ^ (fr & 7)) << 4));
            }
            __builtin_amdgcn_s_setprio(1);
#pragma unroll
            for (int mi = 0; mi < 4; ++mi)
#pragma unroll
                for (int nj = 0; nj < 2; ++nj)
                    acc[mi][nj] = __builtin_amdgcn_mfma_f32_16x16x32_bf16(bfr[nj], af[mi],
                                                                          acc[mi][nj], 0, 0, 0);
            __builtin_amdgcn_s_setprio(0);
        }
        asm volatile("" ::: "memory");
        if (t + 1 < 8) {
            // [pv(t-1):1][S(t+1):4][pv(t):1] -> vmcnt(1): S(t+1) drained, pv(t) floats
            asm volatile("s_waitcnt vmcnt(1)" ::: "memory");
            __builtin_amdgcn_s_barrier();
            asm volatile("" ::: "memory");
        }
    }

    // ---------------- epilogue: pure-register e; shfl over fj; LDS wj-combine
    float S[4] = {0.f, 0.f, 0.f, 0.f};
    float P[4] = {0.f, 0.f, 0.f, 0.f};
#pragma unroll
    for (int mi = 0; mi < 4; ++mi)
#pragma unroll
        for (int nj = 0; nj < 2; ++nj)
#pragma unroll
            for (int r = 0; r < 4; ++r) {
                const float e = exp2f(acc[mi][nj][r] * r0v[mi] * r1v[nj * 4 + r]);
                S[mi] += e;
                P[mi] += e * pv[mi][nj][r];
            }
#pragma unroll
    for (int mi = 0; mi < 4; ++mi) {   // reduce the 4 fj groups (same i)
        S[mi] += __shfl_xor(S[mi], 16); S[mi] += __shfl_xor(S[mi], 32);
        P[mi] += __shfl_xor(P[mi], 16); P[mi] += __shfl_xor(P[mi], 32);
    }
    // cross-wj combine: 4 KB scratch overlays buf0-A ([0,16K)); step-7 reads
    // only buf1 regions ([16K,32K) and [48K,64K)) -> no overlap race.
    float* sc = (float*)smem;          // [S: wj x 128 | P: wj x 128]
    if (lane < 16) {
#pragma unroll
        for (int mi = 0; mi < 4; ++mi) {
            sc[wj * 128 + wi * 64 + mi * 16 + fr] = S[mi];
            sc[512 + wj * 128 + wi * 64 + mi * 16 + fr] = P[mi];
        }
    }
    __syncthreads();
    if (tid < 128) {
        pS[(long)jt * NROWS + ibase + tid] = sc[tid] + sc[128 + tid] + sc[256 + tid] + sc[384 + tid];
        pP[(long)jt * NROWS + ibase + tid] = sc[512 + tid] + sc[640 + tid] + sc[768 + tid] + sc[896 + tid];
    }
}

// ---------------------------------------------------------------- row norms
__global__ __launch_bounds__(256) void rownorm(const bf16_t* __restrict__ Z,
                                               float* __restrict__ rn) {
    const int row  = blockIdx.x * 4 + (threadIdx.x >> 6);
    const int lane = threadIdx.x & 63;
    bf16x8 v = *(const bf16x8*)&Z[(size_t)row * HDIM + lane * 8];
    float s = 0.f;
#pragma unroll
    for (int j = 0; j < 8; ++j) { float f = (float)v[j]; s += f * f; }
#pragma unroll
    for (int off = 32; off > 0; off >>= 1) s += __shfl_xor(s, off);
    if (lane == 0) rn[row] = rsqrtf(s);
}

// ---------------------------------------------------------------- reductions
__global__ __launch_bounds__(256) void reduce_rows(const float* __restrict__ pS,
                                                   const float* __restrict__ pP,
                                                   float* __restrict__ bsum) {
    const int i = blockIdx.x * 256 + threadIdx.x;  // row 0..8191
    float S = 0.f, P = 0.f;
    for (int jb = 0; jb < 64; ++jb) {
        S += pS[jb * NROWS + i];
        P += pP[jb * NROWS + i];
    }
    float t = logf(P / (S + 1e-8f) + 1e-8f);
#pragma unroll
    for (int off = 32; off > 0; off >>= 1) t += __shfl_xor(t, off);
    __shared__ float red[4];
    if ((threadIdx.x & 63) == 0) red[threadIdx.x >> 6] = t;
    __syncthreads();
    if (threadIdx.x == 0) bsum[blockIdx.x] = red[0] + red[1] + red[2] + red[3];
}

__global__ void finalize(const float* __restrict__ bsum, float* __restrict__ loss) {
    float t = (threadIdx.x < 32) ? bsum[threadIdx.x] : 0.f;
#pragma unroll
    for (int off = 32; off > 0; off >>= 1) t += __shfl_xor(t, off);
    if (threadIdx.x == 0) *loss = -(t * (1.0f / 8192.0f));
}

// ---------------------------------------------------------------- launch
extern "C" void kernel_launch(void* const* d_in, const int* in_sizes, int n_in,
                              void* d_out, int out_size, void* d_ws, size_t ws_size,
                              hipStream_t stream) {
    const float* embd0 = (const float*)d_in[0];
    const float* embd1 = (const float*)d_in[1];
    const float* pos   = (const float*)d_in[2];
    const float* W1    = (const float*)d_in[3];
    const float* b1    = (const float*)d_in[4];
    const float* W2    = (const float*)d_in[5];
    const float* b2    = (const float*)d_in[6];
    float* out = (float*)d_out;  // [z0 | z1 | loss]

    char* ws = (char*)d_ws;
    bf16_t* Xb   = (bf16_t*)(ws);               // 16 MB  [16384][512]
    bf16_t* Hb   = (bf16_t*)(ws + 16777216);    // 16 MB
    bf16_t* Zb   = (bf16_t*)(ws + 33554432);    // 16 MB
    bf16_t* W1b  = (bf16_t*)(ws + 50331648);    // 512 KB
    bf16_t* W2b  = (bf16_t*)(ws + 50855936);    // 512 KB
    float*  rn   = (float*)(ws + 51380224);     // 64 KB (rn0|rn1)
    float*  pS   = (float*)(ws + 51445760);     // 2 MB [64][8192]
    float*  pP   = (float*)(ws + 53542912);     // 2 MB
    float*  bsum = (float*)(ws + 55640064);     // 128 B

    cvt_f32_bf16<<<2048, 256, 0, stream>>>(embd0, Xb, 524288);
    cvt_f32_bf16<<<2048, 256, 0, stream>>>(embd1, Xb + 4194304, 524288);
    cvt_f32_bf16<<<128, 256, 0, stream>>>(W1, W1b, 32768);
    cvt_f32_bf16<<<128, 256, 0, stream>>>(W2, W2b, 32768);

    gemm_bt<1><<<dim3(128, 4), 256, 0, stream>>>(Xb, W1b, b1, Hb, nullptr);
    gemm_bt<2><<<dim3(128, 4), 256, 0, stream>>>(Hb, W2b, b2, Zb, out);
    rownorm<<<4096, 256, 0, stream>>>(Zb, rn);
    gemm_pos<<<4096, 512, 0, stream>>>(Zb, Zb + 4194304, rn, rn + NROWS, pos, pS, pP);
    reduce_rows<<<32, 256, 0, stream>>>(pS, pP, bsum);
    finalize<<<1, 64, 0, stream>>>(bsum, out + 8388608);
}

// Round 12
// 181.337 us; speedup vs baseline: 1.1445x; 1.1445x over previous
//
#include <hip/hip_runtime.h>
#include <hip/hip_bf16.h>
#include <cmath>

typedef __bf16 bf16_t;
typedef __bf16 bf16x8 __attribute__((ext_vector_type(8)));
typedef float  f32x4  __attribute__((ext_vector_type(4)));

#define AS1(p) ((__attribute__((address_space(1))) void*)(p))
#define AS3(p) ((__attribute__((address_space(3))) void*)(p))

// N=8192, H=512, TAU=0.5, EPS=1e-8
// exp(x) = exp2(x * log2e / TAU); (1/0.5)*log2e = 2.885390...
#define C_EXP2 2.8853900817779268f
#define NROWS  8192
#define HDIM   512

// ---------------------------------------------------------------- f32->bf16
__global__ __launch_bounds__(256) void cvt_f32_bf16(const float* __restrict__ src,
                                                    bf16_t* __restrict__ dst, int n8) {
    int i = blockIdx.x * 256 + threadIdx.x;
    if (i >= n8) return;
    const f32x4* s4 = (const f32x4*)src;
    f32x4 a = s4[2 * (size_t)i];
    f32x4 b = s4[2 * (size_t)i + 1];
    bf16x8 o;
#pragma unroll
    for (int j = 0; j < 4; ++j) { o[j] = (bf16_t)a[j]; o[4 + j] = (bf16_t)b[j]; }
    *(bf16x8*)(dst + 8 * (size_t)i) = o;
}

// ---------------------------------------------------------------- MLP GEMM (NT)
// 128x128 tile, BK=64, NT=8, 2-deep dbuf, vmcnt(0)/step (proven R8 structure).
// EPI=1: bias+ELU -> bf16   EPI=2: bias -> f32 (d_out) + bf16 copy
template <int EPI>
__global__ __launch_bounds__(256, 2)
void gemm_bt(const bf16_t* __restrict__ A, const bf16_t* __restrict__ B,
             const float* __restrict__ bias,
             bf16_t* __restrict__ outb, float* __restrict__ outf) {
    constexpr int K  = 512;
    constexpr int NT = 8;
    __shared__ __align__(16) char smem[65536];

    const int tid  = threadIdx.x;
    const int lane = tid & 63;
    const int wv   = tid >> 6;
    const int wm   = wv >> 1;
    const int wn   = wv & 1;

    const long ibase = (long)blockIdx.x * 128;
    const long jbase = (long)blockIdx.y * 128;

    const int r8  = lane >> 3;
    const int c16 = lane & 7;
    const long aSrc0 = (ibase + wv * 32 + r8) * (long)K + ((c16 ^ r8) << 3);
    const long bSrc0 = (jbase + wv * 32 + r8) * (long)K + ((c16 ^ r8) << 3);

    f32x4 acc[4][4] = {};
    const int fr = lane & 15;
    const int fj = lane >> 4;
    const int crow = fj << 2;
    const int ccol = fr;

#pragma unroll
    for (int s = 0; s < 4; ++s) {
        const int ro = (wv * 32 + s * 8) * 128;
        __builtin_amdgcn_global_load_lds(AS1(A + aSrc0 + s * 8 * K), AS3(smem + ro), 16, 0, 0);
        __builtin_amdgcn_global_load_lds(AS1(B + bSrc0 + s * 8 * K), AS3(smem + 32768 + ro), 16, 0, 0);
    }
    asm volatile("s_waitcnt vmcnt(0)" ::: "memory");
    __builtin_amdgcn_s_barrier();
    asm volatile("" ::: "memory");

#pragma unroll
    for (int t = 0; t < NT; ++t) {
        if (t + 1 < NT) {
            const int nb = (t + 1) & 1;
#pragma unroll
            for (int s = 0; s < 4; ++s) {
                const int ro = (wv * 32 + s * 8) * 128;
                __builtin_amdgcn_global_load_lds(AS1(A + aSrc0 + s * 8 * K + (t + 1) * 64),
                                                 AS3(smem + nb * 16384 + ro), 16, 0, 0);
                __builtin_amdgcn_global_load_lds(AS1(B + bSrc0 + s * 8 * K + (t + 1) * 64),
                                                 AS3(smem + 32768 + nb * 16384 + ro), 16, 0, 0);
            }
        }
        asm volatile("" ::: "memory");
#pragma unroll
        for (int kk = 0; kk < 2; ++kk) {
            bf16x8 af[4], bfr[4];
#pragma unroll
            for (int m = 0; m < 4; ++m) {
                const int row = wm * 64 + m * 16 + fr;
                af[m] = *(const bf16x8*)(smem + (t & 1) * 16384 + row * 128 +
                                         (((kk * 4 + fj) ^ (fr & 7)) << 4));
            }
#pragma unroll
            for (int n = 0; n < 4; ++n) {
                const int row = wn * 64 + n * 16 + fr;
                bfr[n] = *(const bf16x8*)(smem + 32768 + (t & 1) * 16384 + row * 128 +
                                          (((kk * 4 + fj) ^ (fr & 7)) << 4));
            }
            __builtin_amdgcn_s_setprio(1);
#pragma unroll
            for (int m = 0; m < 4; ++m)
#pragma unroll
                for (int n = 0; n < 4; ++n)
                    acc[m][n] = __builtin_amdgcn_mfma_f32_16x16x32_bf16(af[m], bfr[n],
                                                                        acc[m][n], 0, 0, 0);
            __builtin_amdgcn_s_setprio(0);
        }
        asm volatile("" ::: "memory");
        if (t + 1 < NT) asm volatile("s_waitcnt vmcnt(0)" ::: "memory");
        __builtin_amdgcn_s_barrier();
        asm volatile("" ::: "memory");
    }

#pragma unroll
    for (int m = 0; m < 4; ++m) {
        const long rowb = ibase + wm * 64 + m * 16 + crow;
#pragma unroll
        for (int n = 0; n < 4; ++n) {
            const int col = (int)jbase + wn * 64 + n * 16 + ccol;
            const float bv = bias[col];
#pragma unroll
            for (int r = 0; r < 4; ++r) {
                float v = acc[m][n][r] + bv;
                const long idx = (rowb + r) * HDIM + col;
                if constexpr (EPI == 1) {
                    v = v > 0.f ? v : expm1f(v);  // ELU(alpha=1)
                    outb[idx] = (bf16_t)v;
                } else {
                    outf[idx] = v;
                    outb[idx] = (bf16_t)v;
                }
            }
        }
    }
}

// ---------------------------------------------------------------- GEMM3 + pos
// 128(i) x 128(j) tile, 512 threads = 8 waves: wi=wv>>2, wj=wv&3 (64x32/wave),
// BK=64, NT=8, 2-deep dbuf = 64 KB LDS -> 2 blocks/CU = 4 waves/SIMD.
// R12 change (single variable): within-XCD block order flipped to J-FAST /
// I-SLOW. Per XCD: the 8 owned B-panels (1 MB) stay L2-resident the whole
// pass; each A-panel (128 KB) is reused 8x consecutively -> A fetched once
// (8 MB/XCD) instead of 8x (R11's i-fast order streamed A 8x = ~220 MB of
// L3 refetch; FETCH was 483 MB at 3.2 TB/s = the measured 150 us).
// SWAPPED MFMA: acc[mi][nj] = mfma(bfr[nj], af[mi], .) => D col(lane&15)=i,
// D reg=j -> pos loads directly in fragment layout: pv[4][2] f32x4.
// Ledger/step: issue S(t+1)[4/thread] then pv(t)[1/thread]; end-of-step
// vmcnt(1) drains S(t+1)+pv(t-1), pv(t) floats across the barrier.
__global__ __launch_bounds__(512, 4)
void gemm_pos(const bf16_t* __restrict__ A, const bf16_t* __restrict__ B,
              const float* __restrict__ rn0, const float* __restrict__ rn1,
              const float* __restrict__ pos,
              float* __restrict__ pS, float* __restrict__ pP) {
    constexpr int K = 512;
    // As dbuf: [0,32K) (2 x 16 KB); Bs dbuf: [32K,64K) (2 x 16 KB)
    __shared__ __align__(16) char smem[65536];

    const int tid  = threadIdx.x;
    const int lane = tid & 63;
    const int wv   = tid >> 6;   // 0..7
    const int wi   = wv >> 2;    // 0..1: 64-row (i) slab
    const int wj   = wv & 3;     // 0..3: 32-col (j) slab

    // bijective XCD swizzle, j-fast/i-slow within XCD (4096 blocks % 8 == 0):
    // XCD x owns j-panels [8x,8x+8); idx>>3 = i-tile (slow), idx&7 = j (fast)
    const int flat = blockIdx.x;
    const int xcd  = flat & 7;
    const int idx  = flat >> 3;               // 0..511
    const long ibase = (long)(idx >> 3) * 128;
    const int  jt    = xcd * 8 + (idx & 7);   // 0..63
    const long jbase = (long)jt * 128;

    const int r8  = lane >> 3;
    const int c16 = lane & 7;
    const long aSrc0 = (ibase + wv * 16 + r8) * (long)K + ((c16 ^ r8) << 3);
    const long bSrc0 = (jbase + wv * 16 + r8) * (long)K + ((c16 ^ r8) << 3);

    f32x4 acc[4][2] = {};
    const int fr = lane & 15;   // i within 16 (C col after swap)
    const int fj = lane >> 4;
    const int crow = fj << 2;   // j base within fragment
    const int ccol = fr;

    // scales (prologue loads, drained by vmcnt(0))
    float r0v[4], r1v[8];
#pragma unroll
    for (int mi = 0; mi < 4; ++mi)
        r0v[mi] = rn0[ibase + wi * 64 + mi * 16 + ccol] * C_EXP2;
#pragma unroll
    for (int nj = 0; nj < 2; ++nj)
#pragma unroll
        for (int r = 0; r < 4; ++r)
            r1v[nj * 4 + r] = rn1[jbase + wj * 32 + nj * 16 + crow + r];

    f32x4 pv[4][2];  // pos fragments: pv[mi][nj] = pos[i][j..j+3]
    const float* p00 = pos + (size_t)(ibase + wi * 64 + ccol) * NROWS + jbase + wj * 32 + crow;

    // staging: A,B each 128x64 bf16 = 16 KB/buf; 2 instr/thread each
    auto STAGE = [&](int buf, int t) {
#pragma unroll
        for (int s = 0; s < 2; ++s)
            __builtin_amdgcn_global_load_lds(AS1(A + aSrc0 + s * 8 * K + t * 64),
                                             AS3(smem + buf * 16384 + (wv * 16 + s * 8) * 128), 16, 0, 0);
#pragma unroll
        for (int s = 0; s < 2; ++s)
            __builtin_amdgcn_global_load_lds(AS1(B + bSrc0 + s * 8 * K + t * 64),
                                             AS3(smem + 32768 + buf * 16384 + (wv * 16 + s * 8) * 128), 16, 0, 0);
    };

    // ---------------- prologue: stage(0), full drain, barrier
    STAGE(0, 0);
    asm volatile("s_waitcnt vmcnt(0)" ::: "memory");
    __builtin_amdgcn_s_barrier();
    asm volatile("" ::: "memory");

    // ---------------- pipelined K-loop (fully unrolled)
#pragma unroll
    for (int t = 0; t < 8; ++t) {
        if (t + 1 < 8) STAGE((t + 1) & 1, t + 1);
        asm volatile("" ::: "memory");  // pin: pv(t) issues AFTER S(t+1)
        {
            const int mi = t >> 1, nj = t & 1;   // compile-time
            pv[mi][nj] = *(const f32x4*)(p00 + (size_t)(mi * 16) * NROWS + nj * 16);
        }
        // compute on buf t&1: 2 k-halves x (4 A-frag x 2 B-frag) MFMA
#pragma unroll
        for (int kk = 0; kk < 2; ++kk) {
            bf16x8 af[4], bfr[2];
#pragma unroll
            for (int mi = 0; mi < 4; ++mi) {
                const int row = wi * 64 + mi * 16 + fr;
                af[mi] = *(const bf16x8*)(smem + (t & 1) * 16384 + row * 128 +
                                          (((kk * 4 + fj) ^ (fr & 7)) << 4));
            }
#pragma unroll
            for (int nj = 0; nj < 2; ++nj) {
                const int row = wj * 32 + nj * 16 + fr;
                bfr[nj] = *(const bf16x8*)(smem + 32768 + (t & 1) * 16384 + row * 128 +
                                           (((kk * 4 + fj) ^ (fr & 7)) << 4));
            }
            __builtin_amdgcn_s_setprio(1);
#pragma unroll
            for (int mi = 0; mi < 4; ++mi)
#pragma unroll
                for (int nj = 0; nj < 2; ++nj)
                    acc[mi][nj] = __builtin_amdgcn_mfma_f32_16x16x32_bf16(bfr[nj], af[mi],
                                                                          acc[mi][nj], 0, 0, 0);
            __builtin_amdgcn_s_setprio(0);
        }
        asm volatile("" ::: "memory");
        if (t + 1 < 8) {
            // [pv(t-1):1][S(t+1):4][pv(t):1] -> vmcnt(1): S(t+1) drained, pv(t) floats
            asm volatile("s_waitcnt vmcnt(1)" ::: "memory");
            __builtin_amdgcn_s_barrier();
            asm volatile("" ::: "memory");
        }
    }

    // ---------------- epilogue: pure-register e; shfl over fj; LDS wj-combine
    float S[4] = {0.f, 0.f, 0.f, 0.f};
    float P[4] = {0.f, 0.f, 0.f, 0.f};
#pragma unroll
    for (int mi = 0; mi < 4; ++mi)
#pragma unroll
        for (int nj = 0; nj < 2; ++nj)
#pragma unroll
            for (int r = 0; r < 4; ++r) {
                const float e = exp2f(acc[mi][nj][r] * r0v[mi] * r1v[nj * 4 + r]);
                S[mi] += e;
                P[mi] += e * pv[mi][nj][r];
            }
#pragma unroll
    for (int mi = 0; mi < 4; ++mi) {   // reduce the 4 fj groups (same i)
        S[mi] += __shfl_xor(S[mi], 16); S[mi] += __shfl_xor(S[mi], 32);
        P[mi] += __shfl_xor(P[mi], 16); P[mi] += __shfl_xor(P[mi], 32);
    }
    // cross-wj combine: 4 KB scratch overlays buf0-A ([0,16K)); step-7 reads
    // only buf1 regions ([16K,32K) and [48K,64K)) -> no overlap race.
    float* sc = (float*)smem;          // [S: wj x 128 | P: wj x 128]
    if (lane < 16) {
#pragma unroll
        for (int mi = 0; mi < 4; ++mi) {
            sc[wj * 128 + wi * 64 + mi * 16 + fr] = S[mi];
            sc[512 + wj * 128 + wi * 64 + mi * 16 + fr] = P[mi];
        }
    }
    __syncthreads();
    if (tid < 128) {
        pS[(long)jt * NROWS + ibase + tid] = sc[tid] + sc[128 + tid] + sc[256 + tid] + sc[384 + tid];
        pP[(long)jt * NROWS + ibase + tid] = sc[512 + tid] + sc[640 + tid] + sc[768 + tid] + sc[896 + tid];
    }
}

// ---------------------------------------------------------------- row norms
__global__ __launch_bounds__(256) void rownorm(const bf16_t* __restrict__ Z,
                                               float* __restrict__ rn) {
    const int row  = blockIdx.x * 4 + (threadIdx.x >> 6);
    const int lane = threadIdx.x & 63;
    bf16x8 v = *(const bf16x8*)&Z[(size_t)row * HDIM + lane * 8];
    float s = 0.f;
#pragma unroll
    for (int j = 0; j < 8; ++j) { float f = (float)v[j]; s += f * f; }
#pragma unroll
    for (int off = 32; off > 0; off >>= 1) s += __shfl_xor(s, off);
    if (lane == 0) rn[row] = rsqrtf(s);
}

// ---------------------------------------------------------------- reductions
__global__ __launch_bounds__(256) void reduce_rows(const float* __restrict__ pS,
                                                   const float* __restrict__ pP,
                                                   float* __restrict__ bsum) {
    const int i = blockIdx.x * 256 + threadIdx.x;  // row 0..8191
    float S = 0.f, P = 0.f;
    for (int jb = 0; jb < 64; ++jb) {
        S += pS[jb * NROWS + i];
        P += pP[jb * NROWS + i];
    }
    float t = logf(P / (S + 1e-8f) + 1e-8f);
#pragma unroll
    for (int off = 32; off > 0; off >>= 1) t += __shfl_xor(t, off);
    __shared__ float red[4];
    if ((threadIdx.x & 63) == 0) red[threadIdx.x >> 6] = t;
    __syncthreads();
    if (threadIdx.x == 0) bsum[blockIdx.x] = red[0] + red[1] + red[2] + red[3];
}

__global__ void finalize(const float* __restrict__ bsum, float* __restrict__ loss) {
    float t = (threadIdx.x < 32) ? bsum[threadIdx.x] : 0.f;
#pragma unroll
    for (int off = 32; off > 0; off >>= 1) t += __shfl_xor(t, off);
    if (threadIdx.x == 0) *loss = -(t * (1.0f / 8192.0f));
}

// ---------------------------------------------------------------- launch
extern "C" void kernel_launch(void* const* d_in, const int* in_sizes, int n_in,
                              void* d_out, int out_size, void* d_ws, size_t ws_size,
                              hipStream_t stream) {
    const float* embd0 = (const float*)d_in[0];
    const float* embd1 = (const float*)d_in[1];
    const float* pos   = (const float*)d_in[2];
    const float* W1    = (const float*)d_in[3];
    const float* b1    = (const float*)d_in[4];
    const float* W2    = (const float*)d_in[5];
    const float* b2    = (const float*)d_in[6];
    float* out = (float*)d_out;  // [z0 | z1 | loss]

    char* ws = (char*)d_ws;
    bf16_t* Xb   = (bf16_t*)(ws);               // 16 MB  [16384][512]
    bf16_t* Hb   = (bf16_t*)(ws + 16777216);    // 16 MB
    bf16_t* Zb   = (bf16_t*)(ws + 33554432);    // 16 MB
    bf16_t* W1b  = (bf16_t*)(ws + 50331648);    // 512 KB
    bf16_t* W2b  = (bf16_t*)(ws + 50855936);    // 512 KB
    float*  rn   = (float*)(ws + 51380224);     // 64 KB (rn0|rn1)
    float*  pS   = (float*)(ws + 51445760);     // 2 MB [64][8192]
    float*  pP   = (float*)(ws + 53542912);     // 2 MB
    float*  bsum = (float*)(ws + 55640064);     // 128 B

    cvt_f32_bf16<<<2048, 256, 0, stream>>>(embd0, Xb, 524288);
    cvt_f32_bf16<<<2048, 256, 0, stream>>>(embd1, Xb + 4194304, 524288);
    cvt_f32_bf16<<<128, 256, 0, stream>>>(W1, W1b, 32768);
    cvt_f32_bf16<<<128, 256, 0, stream>>>(W2, W2b, 32768);

    gemm_bt<1><<<dim3(128, 4), 256, 0, stream>>>(Xb, W1b, b1, Hb, nullptr);
    gemm_bt<2><<<dim3(128, 4), 256, 0, stream>>>(Hb, W2b, b2, Zb, out);
    rownorm<<<4096, 256, 0, stream>>>(Zb, rn);
    gemm_pos<<<4096, 512, 0, stream>>>(Zb, Zb + 4194304, rn, rn + NROWS, pos, pS, pP);
    reduce_rows<<<32, 256, 0, stream>>>(pS, pP, bsum);
    finalize<<<1, 64, 0, stream>>>(bsum, out + 8388608);
}